// Round 1
// baseline (619.015 us; speedup 1.0000x reference)
//
#include <hip/hip_runtime.h>
#include <math.h>

#define HW_N   147456           // 384*384
#define NCH    32
#define NBATCH 8
#define NCHUNK 144
#define CP     (HW_N / NCHUNK)  // 1024 positions per block
#define TILE_P 128

// ---------------------------------------------------------------------------
// Phase 1: per-batch channel gram G[b][i][j] = sum_hw q[b,i,hw]*v[b,j,hw]
//          plus channel sums sq[b][c] = sum_hw q[b,c,hw], sv likewise.
// grid (NCHUNK, NBATCH), block 256. Each wave covers all 32x32 pairs on its
// own 32-position sub-slice of a 128-position LDS tile.
// ---------------------------------------------------------------------------
__global__ __launch_bounds__(256, 4) void gram_kernel(
    const float* __restrict__ q, const float* __restrict__ v,
    float* __restrict__ G, float* __restrict__ sq, float* __restrict__ sv)
{
    __shared__ float qs[NCH][130];   // stride 130: even (b64-aligned), 2-way max alias
    __shared__ float vs[NCH][130];

    const int b     = blockIdx.y;
    const int chunk = blockIdx.x;
    const int t     = threadIdx.x;
    const int lane  = t & 63;
    const int w     = t >> 6;        // wave id 0..3
    const int ig    = lane & 7;      // i = 4*ig + ii
    const int jg    = lane >> 3;     // j = 4*jg + jj

    const float* qb = q + (size_t)b * NCH * HW_N;
    const float* vb = v + (size_t)b * NCH * HW_N;

    float acc[4][4];
#pragma unroll
    for (int ii = 0; ii < 4; ++ii)
#pragma unroll
        for (int jj = 0; jj < 4; ++jj) acc[ii][jj] = 0.f;

    float sumq[4] = {0.f, 0.f, 0.f, 0.f};
    float sumv[4] = {0.f, 0.f, 0.f, 0.f};

    const int p_base = chunk * CP;

    for (int tile = 0; tile < CP / TILE_P; ++tile) {
        const int p0 = p_base + tile * TILE_P;
        // ---- stage 32x128 tiles of q and v (float4 global, float2 LDS) ----
#pragma unroll
        for (int k = 0; k < 4; ++k) {
            int f = t + k * 256;         // 0..1023
            int r = f >> 5;              // channel row
            int c = f & 31;              // float4 column (32 per row)
            float4 xq = *(const float4*)(qb + (size_t)r * HW_N + p0 + 4 * c);
            float4 xv = *(const float4*)(vb + (size_t)r * HW_N + p0 + 4 * c);
            *(float2*)&qs[r][4 * c]     = make_float2(xq.x, xq.y);
            *(float2*)&qs[r][4 * c + 2] = make_float2(xq.z, xq.w);
            *(float2*)&vs[r][4 * c]     = make_float2(xv.x, xv.y);
            *(float2*)&vs[r][4 * c + 2] = make_float2(xv.z, xv.w);
            sumq[k] += xq.x + xq.y + xq.z + xq.w;
            sumv[k] += xv.x + xv.y + xv.z + xv.w;
        }
        __syncthreads();
        // ---- compute: wave w owns positions [w*32, w*32+32) ----
        const int pw = w * 32;
#pragma unroll
        for (int p2 = 0; p2 < 32; p2 += 2) {
            float2 qv[4], vv[4];
#pragma unroll
            for (int ii = 0; ii < 4; ++ii)
                qv[ii] = *(const float2*)&qs[4 * ig + ii][pw + p2];
#pragma unroll
            for (int jj = 0; jj < 4; ++jj)
                vv[jj] = *(const float2*)&vs[4 * jg + jj][pw + p2];
#pragma unroll
            for (int ii = 0; ii < 4; ++ii)
#pragma unroll
                for (int jj = 0; jj < 4; ++jj)
                    acc[ii][jj] += qv[ii].x * vv[jj].x + qv[ii].y * vv[jj].y;
        }
        __syncthreads();
    }

    // ---- cross-wave reduction via LDS (reuse qs for G, vs for sums) ----
    float* red  = &qs[0][0];   // 4*1024 <= 32*130
    float* redv = &vs[0][0];   // 2*1024 <= 32*130
#pragma unroll
    for (int ii = 0; ii < 4; ++ii)
#pragma unroll
        for (int jj = 0; jj < 4; ++jj) {
            int i = 4 * ig + ii, j = 4 * jg + jj;
            red[w * 1024 + i * 32 + j] = acc[ii][jj];
        }
#pragma unroll
    for (int k = 0; k < 4; ++k) {
        int f = t + k * 256;
        redv[f]        = sumq[k];
        redv[1024 + f] = sumv[k];
    }
    __syncthreads();
#pragma unroll
    for (int k = 0; k < 4; ++k) {
        int pr = t + k * 256;
        float s = red[pr] + red[1024 + pr] + red[2048 + pr] + red[3072 + pr];
        atomicAdd(&G[b * 1024 + pr], s);
    }
    if (t < 32) {
        float s1 = 0.f, s2 = 0.f;
#pragma unroll
        for (int c = 0; c < 32; ++c) {
            s1 += redv[t * 32 + c];
            s2 += redv[1024 + t * 32 + c];
        }
        atomicAdd(&sq[b * 32 + t], s1);
        atomicAdd(&sv[b * 32 + t], s2);
    }
}

// ---------------------------------------------------------------------------
// Phase 2: logits -> softmax -> M = wo@S@wa, e = wo@(S@ba) + bo. Tiny.
// grid NBATCH blocks x 1024 threads; thread (i = t>>5, j = t&31).
// ---------------------------------------------------------------------------
__global__ __launch_bounds__(1024) void attn_kernel(
    const float* __restrict__ G, const float* __restrict__ sq, const float* __restrict__ sv,
    const float* __restrict__ wa, const float* __restrict__ ba,
    const float* __restrict__ wb, const float* __restrict__ bb,
    const float* __restrict__ wc, const float* __restrict__ bc,
    const float* __restrict__ wo, const float* __restrict__ bo,
    float* __restrict__ M, float* __restrict__ e)
{
    const int b = blockIdx.x;
    const int t = threadIdx.x;
    const int i = t >> 5;
    const int j = t & 31;

    __shared__ float Gs[32][33], T[32][33], Ss[32][33], sba[32];

    Gs[i][j] = G[b * 1024 + i * 32 + j];
    __syncthreads();

    // T[i][d] = sum_c wc[i][c] * G[c][d]   (d = j)
    float acc = 0.f;
#pragma unroll
    for (int c = 0; c < 32; ++c) acc += wc[i * 32 + c] * Gs[c][j];
    T[i][j] = acc;
    __syncthreads();

    // logits
    float L = 0.f;
#pragma unroll
    for (int d = 0; d < 32; ++d) L += T[i][d] * wb[j * 32 + d];
    float sqw = 0.f, svw = 0.f;
#pragma unroll
    for (int c = 0; c < 32; ++c) {
        sqw += wc[i * 32 + c] * sq[b * 32 + c];
        svw += wb[j * 32 + c] * sv[b * 32 + c];
    }
    L += bc[i] * svw + bb[j] * sqw + bc[i] * bb[j] * (float)HW_N;

    // softmax across j (32 lanes; xor masks <=16 stay within 32-lane halves)
    float m = L;
#pragma unroll
    for (int off = 16; off >= 1; off >>= 1) m = fmaxf(m, __shfl_xor(m, off));
    float ex = __expf(L - m);
    float s = ex;
#pragma unroll
    for (int off = 16; off >= 1; off >>= 1) s += __shfl_xor(s, off);
    float S = ex / s;
    Ss[i][j] = S;

    float p = S * ba[j];
#pragma unroll
    for (int off = 16; off >= 1; off >>= 1) p += __shfl_xor(p, off);
    if (j == 0) sba[i] = p;
    __syncthreads();

    // T[i][d] = sum_j S[i][j] * wa[j][d]   (d = j slot)
    float acc2 = 0.f;
#pragma unroll
    for (int jj = 0; jj < 32; ++jj) acc2 += Ss[i][jj] * wa[jj * 32 + j];
    T[i][j] = acc2;
    __syncthreads();

    // M[o][d] = sum_i wo[o][i] * T[i][d]   (o = i slot, d = j slot)
    float acc3 = 0.f;
#pragma unroll
    for (int ii = 0; ii < 32; ++ii) acc3 += wo[i * 32 + ii] * T[ii][j];
    M[b * 1024 + i * 32 + j] = acc3;

    if (j == 0) {
        float ee = bo[i];
#pragma unroll
        for (int ii = 0; ii < 32; ++ii) ee += wo[i * 32 + ii] * sba[ii];
        e[b * 32 + i] = ee;
    }
}

// ---------------------------------------------------------------------------
// Phase 3: out[b,o,p] = sum_d M[b][o][d]*v[b,d,p] + e[b][o] + v[b,o,p]
// grid (NCHUNK, NBATCH), block 256. Thread owns o in {4*oq..+3} (oq=t>>5) and
// positions {2pg, 2pg+1, 2pg+64, 2pg+65} (pg=t&31) of a 128-wide tile.
// ---------------------------------------------------------------------------
__global__ __launch_bounds__(256, 4) void out_kernel(
    const float* __restrict__ v, const float* __restrict__ M,
    const float* __restrict__ e, float* __restrict__ out)
{
    __shared__ float vs[NCH][130];
    __shared__ float Ms[32][33];
    __shared__ float es[32];

    const int b  = blockIdx.y;
    const int t  = threadIdx.x;
    const int pg = t & 31;
    const int oq = t >> 5;

    const float* vb = v + (size_t)b * NCH * HW_N;

#pragma unroll
    for (int k = 0; k < 4; ++k) {
        int f = t + k * 256;
        Ms[f >> 5][f & 31] = M[b * 1024 + f];
    }
    if (t < 32) es[t] = e[b * 32 + t];

    const int p_base = blockIdx.x * CP;

    for (int tile = 0; tile < CP / TILE_P; ++tile) {
        const int p0 = p_base + tile * TILE_P;
#pragma unroll
        for (int k = 0; k < 4; ++k) {
            int f = t + k * 256;
            int r = f >> 5;
            int c = f & 31;
            float4 xv = *(const float4*)(vb + (size_t)r * HW_N + p0 + 4 * c);
            *(float2*)&vs[r][4 * c]     = make_float2(xv.x, xv.y);
            *(float2*)&vs[r][4 * c + 2] = make_float2(xv.z, xv.w);
        }
        __syncthreads();

        float acc[4][4];
#pragma unroll
        for (int oo = 0; oo < 4; ++oo)
#pragma unroll
            for (int pp = 0; pp < 4; ++pp) acc[oo][pp] = 0.f;

#pragma unroll
        for (int d = 0; d < 32; ++d) {
            float2 va = *(const float2*)&vs[d][2 * pg];
            float2 vc = *(const float2*)&vs[d][2 * pg + 64];
#pragma unroll
            for (int oo = 0; oo < 4; ++oo) {
                float mm = Ms[4 * oq + oo][d];
                acc[oo][0] += mm * va.x;
                acc[oo][1] += mm * va.y;
                acc[oo][2] += mm * vc.x;
                acc[oo][3] += mm * vc.y;
            }
        }

#pragma unroll
        for (int oo = 0; oo < 4; ++oo) {
            int o = 4 * oq + oo;
            float eo = es[o];
            float r0 = acc[oo][0] + eo + vs[o][2 * pg];
            float r1 = acc[oo][1] + eo + vs[o][2 * pg + 1];
            float r2 = acc[oo][2] + eo + vs[o][2 * pg + 64];
            float r3 = acc[oo][3] + eo + vs[o][2 * pg + 65];
            size_t base = ((size_t)(b * NCH + o)) * HW_N + p0;
            *(float2*)(out + base + 2 * pg)      = make_float2(r0, r1);
            *(float2*)(out + base + 2 * pg + 64) = make_float2(r2, r3);
        }
        __syncthreads();
    }
}

// ---------------------------------------------------------------------------
extern "C" void kernel_launch(void* const* d_in, const int* in_sizes, int n_in,
                              void* d_out, int out_size, void* d_ws, size_t ws_size,
                              hipStream_t stream) {
    const float* q  = (const float*)d_in[0];
    const float* v  = (const float*)d_in[1];
    const float* wa = (const float*)d_in[2];
    const float* ba = (const float*)d_in[3];
    const float* wb = (const float*)d_in[4];
    const float* bb = (const float*)d_in[5];
    const float* wc = (const float*)d_in[6];
    const float* bc = (const float*)d_in[7];
    const float* wo = (const float*)d_in[8];
    const float* bo = (const float*)d_in[9];
    float* out = (float*)d_out;

    float* G  = (float*)d_ws;            // 8*1024
    float* sq = G + NBATCH * 1024;       // 8*32
    float* sv = sq + NBATCH * 32;        // 8*32
    float* M  = sv + NBATCH * 32;        // 8*1024
    float* e  = M + NBATCH * 1024;       // 8*32

    // ws is poisoned 0xAA before every launch -> zero the accumulators.
    hipMemsetAsync(d_ws, 0, (size_t)(NBATCH * 1024 + 2 * NBATCH * 32) * sizeof(float), stream);

    gram_kernel<<<dim3(NCHUNK, NBATCH), 256, 0, stream>>>(q, v, G, sq, sv);
    attn_kernel<<<NBATCH, 1024, 0, stream>>>(G, sq, sv, wa, ba, wb, bb, wc, bc, wo, bo, M, e);
    out_kernel<<<dim3(NCHUNK, NBATCH), 256, 0, stream>>>(v, M, e, out);
}